// Round 10
// baseline (122.174 us; speedup 1.0000x reference)
//
#include <hip/hip_runtime.h>
#include <hip/hip_fp16.h>

// TRecPolicy round 10: GRU mat-vecs in packed f16 (v_pk_fma_f16 via __hfma2),
// f16 weight/bias block (GRU param set ~400B -> SGPR-resident, no mid-kernel
// s_load stalls). Gate pre-acts accumulate in f16 (pre-scaled by -log2e /
// -2log2e), converted to f32 pairs only at the activation boundary.
// Activations = round-9 shared-rcp f32 groups. MLP + output stay f32.

typedef float v2f __attribute__((ext_vector_type(2)));

__device__ __forceinline__ v2f mk2(float a, float b) { v2f r; r.x = a; r.y = b; return r; }
__device__ __forceinline__ v2f spl(float s) { return mk2(s, s); }
__device__ __forceinline__ v2f fma2(v2f a, v2f b, v2f c) { return __builtin_elementwise_fma(a, b, c); }

__device__ __forceinline__ float fexp2(float x) {
#if __has_builtin(__builtin_amdgcn_exp2f)
    return __builtin_amdgcn_exp2f(x);          // v_exp_f32 (2^x)
#else
    return __expf(0.6931471805599453f * x);
#endif
}
__device__ __forceinline__ float frcp(float x) { return __builtin_amdgcn_rcpf(x); }

#define LOG2E 1.44269504088896f
#define SRZ (-LOG2E)
#define SN  (-2.0f * LOG2E)

// PRE-SCALED activation groups (input already -log2e*x / -2log2e*x).
// One v_rcp serves 4 denominators.
__device__ __forceinline__ void sig4(v2f tA, v2f tB, v2f& oA, v2f& oB) {
    v2f eA = mk2(fexp2(tA.x), fexp2(tA.y));
    v2f eB = mk2(fexp2(tB.x), fexp2(tB.y));
    v2f dA = eA + spl(1.0f);
    v2f dB = eB + spl(1.0f);
    float pA = dA.x * dA.y, pB = dB.x * dB.y;
    float r  = frcp(pA * pB);
    oA = mk2(dA.y, dA.x) * spl(pB * r);
    oB = mk2(dB.y, dB.x) * spl(pA * r);
}
__device__ __forceinline__ void tanh4(v2f tA, v2f tB, v2f& oA, v2f& oB) {
    v2f eA = mk2(fexp2(tA.x), fexp2(tA.y));
    v2f eB = mk2(fexp2(tB.x), fexp2(tB.y));
    v2f dA = eA + spl(1.0f);
    v2f dB = eB + spl(1.0f);
    float pA = dA.x * dA.y, pB = dB.x * dB.y;
    float r2 = frcp(pA * pB) * 2.0f;
    oA = fma2(mk2(dA.y, dA.x), spl(pB * r2), spl(-1.0f));
    oB = fma2(mk2(dB.y, dB.x), spl(pA * r2), spl(-1.0f));
}

__device__ __forceinline__ v2f h2f(__half2 v) { return mk2(__low2float(v), __high2float(v)); }
__device__ __forceinline__ __half2 f2h(v2f v) { return __floats2half2_rn(v.x, v.y); }

// Packed parameter block. GRU section in f16 pairs (pair pp = output rows
// (2pp,2pp+1); element [pp][c] = scale * {W[2pp][c], W[2pp+1][c]}), scales:
// rows 0..7 (r,z) -> SRZ, rows 8..11 (n) -> SN. MLP/out section f32.
struct PK {
    __half2 wiu[6][2];   // slot   0: w_ih_up (12x2)
    __half2 whu[6][4];   // slot  12: w_hh_up (12x4)
    __half2 wid[6][4];   // slot  36: w_ih_dn (12x4)
    __half2 whd[6][4];   // slot  60: w_hh_dn (12x4)
    __half2 bsu[4];      // slot  84: SRZ*(b_ih_up+b_hh_up) rows 0..7
    __half2 bsd[4];      // slot  88
    __half2 binu[2];     // slot  92: SN*b_ih_up rows 8..11
    __half2 bhnu[2];     // slot  94
    __half2 bind[2];     // slot  96
    __half2 bhnd[2];     // slot  98  -> 100 half2 = 400 B
    v2f w1p[2][8];       // v-slot 0: SN*w1
    v2f w2p[2][4];       // v-slot 16: SN*w2
    v2f b1p[2];          // v-slot 24
    v2f b2p[2];          // v-slot 26
    v2f wo01;            // v-slot 28: {w_out[0], w_out[1]}
    v2f wo23;            // v-slot 29
    v2f wo4bo;           // v-slot 30: {w_out[4], b_out[0]}
};

__global__ void repack_kernel(
    const float* __restrict__ w_ih_up, const float* __restrict__ w_hh_up,
    const float* __restrict__ b_ih_up, const float* __restrict__ b_hh_up,
    const float* __restrict__ w1, const float* __restrict__ b1,
    const float* __restrict__ w2, const float* __restrict__ b2,
    const float* __restrict__ w_ih_dn, const float* __restrict__ w_hh_dn,
    const float* __restrict__ b_ih_dn, const float* __restrict__ b_hh_dn,
    const float* __restrict__ w_out, const float* __restrict__ b_out,
    PK* __restrict__ pk)
{
    const int t = threadIdx.x;
    if (t < 100) {                       // f16 slots
        float a, b;
        if (t < 12)      { int pp = t >> 1, c = t & 1;            float s = (pp < 4) ? SRZ : SN;
                           a = s * w_ih_up[4*pp+c];   b = s * w_ih_up[4*pp+2+c]; }
        else if (t < 36) { int i = t-12, pp = i >> 2, c = i & 3;  float s = (pp < 4) ? SRZ : SN;
                           a = s * w_hh_up[8*pp+c];   b = s * w_hh_up[8*pp+4+c]; }
        else if (t < 60) { int i = t-36, pp = i >> 2, c = i & 3;  float s = (pp < 4) ? SRZ : SN;
                           a = s * w_ih_dn[8*pp+c];   b = s * w_ih_dn[8*pp+4+c]; }
        else if (t < 84) { int i = t-60, pp = i >> 2, c = i & 3;  float s = (pp < 4) ? SRZ : SN;
                           a = s * w_hh_dn[8*pp+c];   b = s * w_hh_dn[8*pp+4+c]; }
        else if (t < 88) { int p = t-84;
                           a = SRZ * (b_ih_up[2*p]   + b_hh_up[2*p]);
                           b = SRZ * (b_ih_up[2*p+1] + b_hh_up[2*p+1]); }
        else if (t < 92) { int p = t-88;
                           a = SRZ * (b_ih_dn[2*p]   + b_hh_dn[2*p]);
                           b = SRZ * (b_ih_dn[2*p+1] + b_hh_dn[2*p+1]); }
        else if (t < 94) { int p = t-92; a = SN * b_ih_up[8+2*p]; b = SN * b_ih_up[9+2*p]; }
        else if (t < 96) { int p = t-94; a = SN * b_hh_up[8+2*p]; b = SN * b_hh_up[9+2*p]; }
        else if (t < 98) { int p = t-96; a = SN * b_ih_dn[8+2*p]; b = SN * b_ih_dn[9+2*p]; }
        else             { int p = t-98; a = SN * b_hh_dn[8+2*p]; b = SN * b_hh_dn[9+2*p]; }
        reinterpret_cast<__half2*>(pk)[t] = __floats2half2_rn(a, b);
    } else if (t < 131) {                // f32 slots
        const int v = t - 100;
        float a, b;
        if (v < 16)      { int pp = v >> 3, c = v & 7;  a = SN * w1[16*pp+c]; b = SN * w1[16*pp+8+c]; }
        else if (v < 24) { int u = v-16, pp = u >> 2, c = u & 3;
                           a = SN * w2[8*pp+c]; b = SN * w2[8*pp+4+c]; }
        else if (v < 26) { int p = v-24; a = SN * b1[2*p]; b = SN * b1[2*p+1]; }
        else if (v < 28) { int p = v-26; a = SN * b2[2*p]; b = SN * b2[2*p+1]; }
        else if (v == 28) { a = w_out[0]; b = w_out[1]; }
        else if (v == 29) { a = w_out[2]; b = w_out[3]; }
        else              { a = w_out[4]; b = b_out[0]; }
        v2f* vp = reinterpret_cast<v2f*>(reinterpret_cast<char*>(pk) + 100 * sizeof(__half2));
        vp[v] = mk2(a, b);
    }
}

// acc += pair-packed f16 4-dot over inputs (a.lo, a.hi, b.lo, b.hi)
__device__ __forceinline__ __half2 dot4h(const __half2* __restrict__ wp,
                                         __half2 a, __half2 b, __half2 acc) {
    acc = __hfma2(__low2half2(a),  wp[0], acc);
    acc = __hfma2(__high2half2(a), wp[1], acc);
    acc = __hfma2(__low2half2(b),  wp[2], acc);
    acc = __hfma2(__high2half2(b), wp[3], acc);
    return acc;
}

__global__ void __launch_bounds__(256) trec_kernel(
    const float* __restrict__ x, const PK* __restrict__ pk,
    float* __restrict__ out, int n)
{
    const int row = blockIdx.x * blockDim.x + threadIdx.x;
    if (row >= n) return;

    // ---- load 18-float row as 9x float2 ----
    float xv[18];
    {
        const float2* xp = reinterpret_cast<const float2*>(x + (size_t)row * 18u);
        #pragma unroll
        for (int k = 0; k < 9; ++k) {
            float2 v = xp[k];
            xv[2 * k] = v.x;
            xv[2 * k + 1] = v.y;
        }
    }

    v2f hA = spl(0.f), hB = spl(0.f);
    __half2 h01 = __floats2half2_rn(0.f, 0.f), h23 = h01;
    __half2 hup01[7], hup23[7];

    // ---- up GRU: i = 6..0, xi = [j[i], jd[i]] ----
    #pragma unroll
    for (int s = 0; s < 7; ++s) {
        const int i = 6 - s;
        const __half2 xh  = __floats2half2_rn(xv[4 + i], xv[11 + i]);
        const __half2 x0s = __low2half2(xh), x1s = __high2half2(xh);

        v2f rzf[4];
        #pragma unroll
        for (int p = 0; p < 4; ++p) {   // pairs: rows (0,1),(2,3)=r; (4,5),(6,7)=z
            __half2 acc = __hfma2(x1s, pk->wiu[p][1], __hfma2(x0s, pk->wiu[p][0], pk->bsu[p]));
            acc = dot4h(pk->whu[p], h01, h23, acc);
            rzf[p] = h2f(acc);
        }
        v2f rA, rB, zA, zB;
        sig4(rzf[0], rzf[1], rA, rB);
        sig4(rzf[2], rzf[3], zA, zB);

        // n gates: rows (8,9),(10,11); gi and gh separate for r * gh
        __half2 giAh = __hfma2(x1s, pk->wiu[4][1], __hfma2(x0s, pk->wiu[4][0], pk->binu[0]));
        __half2 giBh = __hfma2(x1s, pk->wiu[5][1], __hfma2(x0s, pk->wiu[5][0], pk->binu[1]));
        __half2 ghAh = dot4h(pk->whu[4], h01, h23, pk->bhnu[0]);
        __half2 ghBh = dot4h(pk->whu[5], h01, h23, pk->bhnu[1]);
        v2f nA, nB;
        tanh4(fma2(rA, h2f(ghAh), h2f(giAh)), fma2(rB, h2f(ghBh), h2f(giBh)), nA, nB);

        hA = fma2(zA, hA - nA, nA);     // (1-z)*n + z*h
        hB = fma2(zB, hB - nB, nB);
        h01 = f2h(hA); h23 = f2h(hB);
        hup01[s] = h01; hup23[s] = h23;
    }

    // ---- MLP (f32): tanh([obs,h] @ w1.T + b1) -> tanh(@ w2.T + b2) ----
    const v2f* vblk = reinterpret_cast<const v2f*>(reinterpret_cast<const char*>(pk) + 100 * sizeof(__half2));
    {
        float in8[8] = { xv[0], xv[1], xv[2], xv[3], hA.x, hA.y, hB.x, hB.y };
        v2f a0 = vblk[24], a1 = vblk[25];               // b1p
        #pragma unroll
        for (int d = 0; d < 8; ++d) {
            a0 = fma2(spl(in8[d]), vblk[d], a0);        // w1p[0][d]
            a1 = fma2(spl(in8[d]), vblk[8 + d], a1);    // w1p[1][d]
        }
        v2f t1A, t1B;
        tanh4(a0, a1, t1A, t1B);
        v2f c0 = vblk[26], c1 = vblk[27];               // b2p
        c0 = fma2(spl(t1A.x), vblk[16], c0); c0 = fma2(spl(t1A.y), vblk[17], c0);
        c0 = fma2(spl(t1B.x), vblk[18], c0); c0 = fma2(spl(t1B.y), vblk[19], c0);
        c1 = fma2(spl(t1A.x), vblk[20], c1); c1 = fma2(spl(t1A.y), vblk[21], c1);
        c1 = fma2(spl(t1B.x), vblk[22], c1); c1 = fma2(spl(t1B.y), vblk[23], c1);
        tanh4(c0, c1, hA, hB);
        h01 = f2h(hA); h23 = f2h(hB);
    }

    // ---- down GRU: i = 0..6, xi = hup[i]; act = [h, j[i]] @ w_out.T + b_out ----
    const v2f wo01 = vblk[28], wo23 = vblk[29], wo4bo = vblk[30];
    float acts[7];
    #pragma unroll
    for (int i = 0; i < 7; ++i) {
        const __half2 xi01 = hup01[i], xi23 = hup23[i];

        v2f rzf[4];
        #pragma unroll
        for (int p = 0; p < 4; ++p) {
            __half2 acc = dot4h(pk->wid[p], xi01, xi23, pk->bsd[p]);
            acc = dot4h(pk->whd[p], h01, h23, acc);
            rzf[p] = h2f(acc);
        }
        v2f rA, rB, zA, zB;
        sig4(rzf[0], rzf[1], rA, rB);
        sig4(rzf[2], rzf[3], zA, zB);

        __half2 giAh = dot4h(pk->wid[4], xi01, xi23, pk->bind[0]);
        __half2 giBh = dot4h(pk->wid[5], xi01, xi23, pk->bind[1]);
        __half2 ghAh = dot4h(pk->whd[4], h01, h23, pk->bhnd[0]);
        __half2 ghBh = dot4h(pk->whd[5], h01, h23, pk->bhnd[1]);
        v2f nA, nB;
        tanh4(fma2(rA, h2f(ghAh), h2f(giAh)), fma2(rB, h2f(ghBh), h2f(giBh)), nA, nB);

        hA = fma2(zA, hA - nA, nA);
        hB = fma2(zB, hB - nB, nB);
        h01 = f2h(hA); h23 = f2h(hB);

        v2f t = fma2(hA, wo01, mk2(wo4bo.y, 0.f));
        t = fma2(hB, wo23, t);
        acts[i] = fmaf(xv[4 + i], wo4bo.x, t.x + t.y);
    }

    // ---- store (n x 7, row-major) ----
    float* op = out + (size_t)row * 7u;
    #pragma unroll
    for (int i = 0; i < 7; ++i) op[i] = acts[i];
}

extern "C" void kernel_launch(void* const* d_in, const int* in_sizes, int n_in,
                              void* d_out, int out_size, void* d_ws, size_t ws_size,
                              hipStream_t stream)
{
    const float* x       = (const float*)d_in[0];
    const float* w_ih_up = (const float*)d_in[1];
    const float* w_hh_up = (const float*)d_in[2];
    const float* b_ih_up = (const float*)d_in[3];
    const float* b_hh_up = (const float*)d_in[4];
    const float* w1      = (const float*)d_in[5];
    const float* b1      = (const float*)d_in[6];
    const float* w2      = (const float*)d_in[7];
    const float* b2      = (const float*)d_in[8];
    const float* w_ih_dn = (const float*)d_in[9];
    const float* w_hh_dn = (const float*)d_in[10];
    const float* b_ih_dn = (const float*)d_in[11];
    const float* b_hh_dn = (const float*)d_in[12];
    const float* w_out   = (const float*)d_in[13];
    const float* b_out   = (const float*)d_in[14];
    float* out = (float*)d_out;

    const int n = in_sizes[0] / 18;
    const int block = 256;
    const int grid = (n + block - 1) / block;

    repack_kernel<<<1, 192, 0, stream>>>(
        w_ih_up, w_hh_up, b_ih_up, b_hh_up,
        w1, b1, w2, b2,
        w_ih_dn, w_hh_dn, b_ih_dn, b_hh_dn,
        w_out, b_out, (PK*)d_ws);

    trec_kernel<<<grid, block, 0, stream>>>(
        x, (const PK*)d_ws, out, n);
}

// Round 11
// 111.473 us; speedup vs baseline: 1.0960x; 1.0960x over previous
//
#include <hip/hip_runtime.h>
#include <hip/hip_fp16.h>

// TRecPolicy round 11: round-8 kernel (best, 105.8us) + hup buffer stored as
// __half2 (-14 VGPR) + __launch_bounds__(256,6) to lift occupancy (39% -> 55%+).
// Math identical to round 8 otherwise.

typedef float v2f __attribute__((ext_vector_type(2)));

__device__ __forceinline__ v2f mk2(float a, float b) { v2f r; r.x = a; r.y = b; return r; }
__device__ __forceinline__ v2f spl(float s) { return mk2(s, s); }
__device__ __forceinline__ v2f fma2(v2f a, v2f b, v2f c) { return __builtin_elementwise_fma(a, b, c); }

__device__ __forceinline__ float fexp2(float x) {
#if __has_builtin(__builtin_amdgcn_exp2f)
    return __builtin_amdgcn_exp2f(x);          // v_exp_f32 (2^x)
#else
    return __expf(0.6931471805599453f * x);
#endif
}
__device__ __forceinline__ float frcp(float x) { return __builtin_amdgcn_rcpf(x); }

#define LOG2E 1.44269504088896f

// PRE-SCALED activations: input is already -log2e*x (sig) / -2log2e*x (tanh).
__device__ __forceinline__ v2f sig2s(v2f t) {          // 1/(1+2^t)
    v2f e = mk2(fexp2(t.x), fexp2(t.y));
    v2f d = e + spl(1.0f);
    return mk2(frcp(d.x), frcp(d.y));
}
__device__ __forceinline__ v2f tanh2s(v2f t) {         // 2/(1+2^t) - 1
    v2f e = mk2(fexp2(t.x), fexp2(t.y));
    v2f d = e + spl(1.0f);
    v2f r = mk2(frcp(d.x), frcp(d.y));
    return fma2(r, spl(2.0f), spl(-1.0f));
}

__device__ __forceinline__ __half2 f2h(v2f v) { return __floats2half2_rn(v.x, v.y); }
__device__ __forceinline__ v2f h2f(__half2 v) { return mk2(__low2float(v), __high2float(v)); }

// Packed parameter block layout (all v2f, 131 total). Pair pp covers output
// rows (2pp, 2pp+1); element [pp][c] = scale * {W[2pp][c], W[2pp+1][c]}.
// Scales: gate rows 0..7 (r,z) -> -LOG2E; rows 8..11 (n) -> -2LOG2E;
//         w1/b1/w2/b2 -> -2LOG2E; w_out/b_out unscaled.
struct PK {
    v2f wiu[6][2];   // off   0: w_ih_up (12x2), scaled
    v2f whu[6][4];   // off  12: w_hh_up (12x4), scaled
    v2f wid[6][4];   // off  36: w_ih_dn (12x4), scaled
    v2f whd[6][4];   // off  60: w_hh_dn (12x4), scaled
    v2f w1p[2][8];   // off  84: w1 (4x8), scaled
    v2f w2p[2][4];   // off 100: w2 (4x4), scaled
    v2f bsu[4];      // off 108: (b_ih_up+b_hh_up) rows 0..7, scaled
    v2f bsd[4];      // off 112: (b_ih_dn+b_hh_dn) rows 0..7, scaled
    v2f binu[2];     // off 116: b_ih_up rows 8..11, scaled
    v2f bhnu[2];     // off 118: b_hh_up rows 8..11, scaled
    v2f bind[2];     // off 120: b_ih_dn rows 8..11, scaled
    v2f bhnd[2];     // off 122: b_hh_dn rows 8..11, scaled
    v2f b1p[2];      // off 124: scaled
    v2f b2p[2];      // off 126: scaled
    v2f wo01;        // off 128: {w_out[0], w_out[1]}
    v2f wo23;        // off 129: {w_out[2], w_out[3]}
    v2f wo4bo;       // off 130: {w_out[4], b_out[0]}
};

#define SRZ (-LOG2E)
#define SN  (-2.0f * LOG2E)

__global__ void repack_kernel(
    const float* __restrict__ w_ih_up, const float* __restrict__ w_hh_up,
    const float* __restrict__ b_ih_up, const float* __restrict__ b_hh_up,
    const float* __restrict__ w1, const float* __restrict__ b1,
    const float* __restrict__ w2, const float* __restrict__ b2,
    const float* __restrict__ w_ih_dn, const float* __restrict__ w_hh_dn,
    const float* __restrict__ b_ih_dn, const float* __restrict__ b_hh_dn,
    const float* __restrict__ w_out, const float* __restrict__ b_out,
    float2* __restrict__ pk)
{
    const int t = threadIdx.x;
    if (t < 12)       { int pp = t >> 1, c = t & 1;           float s = (pp < 4) ? SRZ : SN;
                        pk[t] = make_float2(s * w_ih_up[4*pp+c],  s * w_ih_up[4*pp+2+c]); }
    else if (t < 36)  { int i = t-12, pp = i >> 2, c = i & 3;  float s = (pp < 4) ? SRZ : SN;
                        pk[t] = make_float2(s * w_hh_up[8*pp+c],  s * w_hh_up[8*pp+4+c]); }
    else if (t < 60)  { int i = t-36, pp = i >> 2, c = i & 3;  float s = (pp < 4) ? SRZ : SN;
                        pk[t] = make_float2(s * w_ih_dn[8*pp+c],  s * w_ih_dn[8*pp+4+c]); }
    else if (t < 84)  { int i = t-60, pp = i >> 2, c = i & 3;  float s = (pp < 4) ? SRZ : SN;
                        pk[t] = make_float2(s * w_hh_dn[8*pp+c],  s * w_hh_dn[8*pp+4+c]); }
    else if (t < 100) { int i = t-84, pp = i >> 3, c = i & 7;
                        pk[t] = make_float2(SN * w1[16*pp+c],     SN * w1[16*pp+8+c]); }
    else if (t < 108) { int i = t-100, pp = i >> 2, c = i & 3;
                        pk[t] = make_float2(SN * w2[8*pp+c],      SN * w2[8*pp+4+c]); }
    else if (t < 112) { int p = t-108;
                        pk[t] = make_float2(SRZ * (b_ih_up[2*p]   + b_hh_up[2*p]),
                                            SRZ * (b_ih_up[2*p+1] + b_hh_up[2*p+1])); }
    else if (t < 116) { int p = t-112;
                        pk[t] = make_float2(SRZ * (b_ih_dn[2*p]   + b_hh_dn[2*p]),
                                            SRZ * (b_ih_dn[2*p+1] + b_hh_dn[2*p+1])); }
    else if (t < 118) { int p = t-116; pk[t] = make_float2(SN * b_ih_up[8+2*p], SN * b_ih_up[9+2*p]); }
    else if (t < 120) { int p = t-118; pk[t] = make_float2(SN * b_hh_up[8+2*p], SN * b_hh_up[9+2*p]); }
    else if (t < 122) { int p = t-120; pk[t] = make_float2(SN * b_ih_dn[8+2*p], SN * b_ih_dn[9+2*p]); }
    else if (t < 124) { int p = t-122; pk[t] = make_float2(SN * b_hh_dn[8+2*p], SN * b_hh_dn[9+2*p]); }
    else if (t < 126) { int p = t-124; pk[t] = make_float2(SN * b1[2*p], SN * b1[2*p+1]); }
    else if (t < 128) { int p = t-126; pk[t] = make_float2(SN * b2[2*p], SN * b2[2*p+1]); }
    else if (t == 128) pk[t] = make_float2(w_out[0], w_out[1]);
    else if (t == 129) pk[t] = make_float2(w_out[2], w_out[3]);
    else if (t == 130) pk[t] = make_float2(w_out[4], b_out[0]);
}

// acc += pair-packed 4-dot: wp[c] = {W[2pp][c], W[2pp+1][c]}, input (a.x,a.y,b.x,b.y)
__device__ __forceinline__ v2f dot4p(const v2f* __restrict__ wp, v2f a, v2f b, v2f acc) {
    acc = fma2(spl(a.x), wp[0], acc);
    acc = fma2(spl(a.y), wp[1], acc);
    acc = fma2(spl(b.x), wp[2], acc);
    acc = fma2(spl(b.y), wp[3], acc);
    return acc;
}

__global__ void __launch_bounds__(256, 6) trec_kernel(
    const float* __restrict__ x, const PK* __restrict__ pk,
    float* __restrict__ out, int n)
{
    const int row = blockIdx.x * blockDim.x + threadIdx.x;
    if (row >= n) return;

    // ---- load 18-float row as 9x float2 ----
    float xv[18];
    {
        const float2* xp = reinterpret_cast<const float2*>(x + (size_t)row * 18u);
        #pragma unroll
        for (int k = 0; k < 9; ++k) {
            float2 v = xp[k];
            xv[2 * k] = v.x;
            xv[2 * k + 1] = v.y;
        }
    }

    v2f hA = spl(0.f), hB = spl(0.f);
    __half2 hup01[7], hup23[7];        // hup stored compressed (f16) to save VGPRs

    // ---- up GRU: i = 6..0, xi = [j[i], jd[i]] ----
    #pragma unroll
    for (int s = 0; s < 7; ++s) {
        const int i = 6 - s;
        const v2f X0 = spl(xv[4 + i]);
        const v2f X1 = spl(xv[11 + i]);

        v2f rz[4];
        #pragma unroll
        for (int p = 0; p < 4; ++p) {          // pairs: rows (0,1),(2,3)=r; (4,5),(6,7)=z
            v2f acc = pk->bsu[p];
            acc = fma2(X0, pk->wiu[p][0], acc);
            acc = fma2(X1, pk->wiu[p][1], acc);
            acc = dot4p(pk->whu[p], hA, hB, acc);
            rz[p] = acc;
        }
        v2f rA = sig2s(rz[0]), rB = sig2s(rz[1]);
        v2f zA = sig2s(rz[2]), zB = sig2s(rz[3]);

        // n gates: rows (8,9),(10,11); gi and gh separate for r * gh
        v2f giA = fma2(X1, pk->wiu[4][1], fma2(X0, pk->wiu[4][0], pk->binu[0]));
        v2f giB = fma2(X1, pk->wiu[5][1], fma2(X0, pk->wiu[5][0], pk->binu[1]));
        v2f ghA = dot4p(pk->whu[4], hA, hB, pk->bhnu[0]);
        v2f ghB = dot4p(pk->whu[5], hA, hB, pk->bhnu[1]);
        v2f nA = tanh2s(fma2(rA, ghA, giA));
        v2f nB = tanh2s(fma2(rB, ghB, giB));

        hA = fma2(zA, hA - nA, nA);            // (1-z)*n + z*h
        hB = fma2(zB, hB - nB, nB);
        hup01[s] = f2h(hA); hup23[s] = f2h(hB);
    }

    // ---- MLP: tanh([obs,h] @ w1.T + b1) -> tanh(@ w2.T + b2) ----
    {
        float in8[8] = { xv[0], xv[1], xv[2], xv[3], hA.x, hA.y, hB.x, hB.y };
        v2f a0 = pk->b1p[0], a1 = pk->b1p[1];
        #pragma unroll
        for (int d = 0; d < 8; ++d) {
            a0 = fma2(spl(in8[d]), pk->w1p[0][d], a0);
            a1 = fma2(spl(in8[d]), pk->w1p[1][d], a1);
        }
        v2f t1A = tanh2s(a0), t1B = tanh2s(a1);
        v2f c0 = dot4p(pk->w2p[0], t1A, t1B, pk->b2p[0]);
        v2f c1 = dot4p(pk->w2p[1], t1A, t1B, pk->b2p[1]);
        hA = tanh2s(c0); hB = tanh2s(c1);
    }

    // ---- down GRU: i = 0..6, xi = hup[i]; act = [h, j[i]] @ w_out.T + b_out ----
    float acts[7];
    #pragma unroll
    for (int i = 0; i < 7; ++i) {
        const v2f xiA = h2f(hup01[i]), xiB = h2f(hup23[i]);

        v2f rz[4];
        #pragma unroll
        for (int p = 0; p < 4; ++p) {
            v2f acc = pk->bsd[p];
            acc = dot4p(pk->wid[p], xiA, xiB, acc);
            acc = dot4p(pk->whd[p], hA, hB, acc);
            rz[p] = acc;
        }
        v2f rA = sig2s(rz[0]), rB = sig2s(rz[1]);
        v2f zA = sig2s(rz[2]), zB = sig2s(rz[3]);

        v2f giA = dot4p(pk->wid[4], xiA, xiB, pk->bind[0]);
        v2f giB = dot4p(pk->wid[5], xiA, xiB, pk->bind[1]);
        v2f ghA = dot4p(pk->whd[4], hA, hB, pk->bhnd[0]);
        v2f ghB = dot4p(pk->whd[5], hA, hB, pk->bhnd[1]);
        v2f nA = tanh2s(fma2(rA, ghA, giA));
        v2f nB = tanh2s(fma2(rB, ghB, giB));

        hA = fma2(zA, hA - nA, nA);
        hB = fma2(zB, hB - nB, nB);

        v2f t = fma2(hA, pk->wo01, mk2(pk->wo4bo.y, 0.f));
        t = fma2(hB, pk->wo23, t);
        acts[i] = fmaf(xv[4 + i], pk->wo4bo.x, t.x + t.y);
    }

    // ---- store (n x 7, row-major) ----
    float* op = out + (size_t)row * 7u;
    #pragma unroll
    for (int i = 0; i < 7; ++i) op[i] = acts[i];
}

extern "C" void kernel_launch(void* const* d_in, const int* in_sizes, int n_in,
                              void* d_out, int out_size, void* d_ws, size_t ws_size,
                              hipStream_t stream)
{
    const float* x       = (const float*)d_in[0];
    const float* w_ih_up = (const float*)d_in[1];
    const float* w_hh_up = (const float*)d_in[2];
    const float* b_ih_up = (const float*)d_in[3];
    const float* b_hh_up = (const float*)d_in[4];
    const float* w1      = (const float*)d_in[5];
    const float* b1      = (const float*)d_in[6];
    const float* w2      = (const float*)d_in[7];
    const float* b2      = (const float*)d_in[8];
    const float* w_ih_dn = (const float*)d_in[9];
    const float* w_hh_dn = (const float*)d_in[10];
    const float* b_ih_dn = (const float*)d_in[11];
    const float* b_hh_dn = (const float*)d_in[12];
    const float* w_out   = (const float*)d_in[13];
    const float* b_out   = (const float*)d_in[14];
    float* out = (float*)d_out;

    const int n = in_sizes[0] / 18;
    const int block = 256;
    const int grid = (n + block - 1) / block;

    repack_kernel<<<1, 192, 0, stream>>>(
        w_ih_up, w_hh_up, b_ih_up, b_hh_up,
        w1, b1, w2, b2,
        w_ih_dn, w_hh_dn, b_ih_dn, b_hh_dn,
        w_out, b_out, (float2*)d_ws);

    trec_kernel<<<grid, block, 0, stream>>>(
        x, (const PK*)d_ws, out, n);
}